// Round 4
// baseline (62.598 us; speedup 1.0000x reference)
//
#include <hip/hip_runtime.h>

// zs: (V=2, B=8192, F=4096) fp32 row-major -> N = 16384 rows, F = 4096 contiguous.
// loss = mean_f[ (s2c^2 - s4c) / (N-1)^3 ] via raw moments S1..S4 per feature.
constexpr int F_DIM = 4096;
constexpr int TPB = 256;
constexpr int FEAT_PER_BLOCK = TPB * 4;   // each thread owns one float4 (4 features)

typedef float vfloat4 __attribute__((ext_vector_type(4)));

// ---------------- Pass 1: streaming raw-moment partials ----------------
// grid = (F/1024, nchunk). Each thread reads one float4 per row for
// rows_per_chunk rows; 8-row unroll keeps 8 dwordx4 nontemporal loads in
// flight (8 KB/wave outstanding vs ~10 KB/CU Little's-law need).
__global__ void __launch_bounds__(TPB) cov_pass1(
    const float* __restrict__ zs, float4* __restrict__ part, int rows_per_chunk) {
  const int f4 = blockIdx.x * TPB + threadIdx.x;         // float4 column index
  const int chunk = blockIdx.y;
  const size_t row0 = (size_t)chunk * rows_per_chunk;
  const vfloat4* __restrict__ src =
      reinterpret_cast<const vfloat4*>(zs) + row0 * (F_DIM / 4) + f4;
  const size_t rstride = F_DIM / 4;

  float s1[4] = {0.f, 0.f, 0.f, 0.f};
  float s2[4] = {0.f, 0.f, 0.f, 0.f};
  float s3[4] = {0.f, 0.f, 0.f, 0.f};
  float s4[4] = {0.f, 0.f, 0.f, 0.f};

  int r = 0;
  for (; r + 8 <= rows_per_chunk; r += 8) {
    vfloat4 zz[8];
#pragma unroll
    for (int u = 0; u < 8; ++u)
      zz[u] = __builtin_nontemporal_load(&src[(size_t)(r + u) * rstride]);
#pragma unroll
    for (int u = 0; u < 8; ++u) {
#pragma unroll
      for (int j = 0; j < 4; ++j) {
        float x = zz[u][j];
        float x2 = x * x;
        s1[j] += x;
        s2[j] = fmaf(x, x, s2[j]);
        s3[j] = fmaf(x2, x, s3[j]);
        s4[j] = fmaf(x2, x2, s4[j]);
      }
    }
  }
  for (; r < rows_per_chunk; ++r) {          // tail (unused for pow2 sizes)
    vfloat4 z = __builtin_nontemporal_load(&src[(size_t)r * rstride]);
#pragma unroll
    for (int j = 0; j < 4; ++j) {
      float x = z[j];
      float x2 = x * x;
      s1[j] += x;
      s2[j] = fmaf(x, x, s2[j]);
      s3[j] = fmaf(x2, x, s3[j]);
      s4[j] = fmaf(x2, x2, s4[j]);
    }
  }

  float4* dst = part + (size_t)chunk * F_DIM + (size_t)f4 * 4;
#pragma unroll
  for (int j = 0; j < 4; ++j)
    dst[j] = make_float4(s1[j], s2[j], s3[j], s4[j]);
}

// ---------------- Pass 2: fp64 combine + loss, 256 blocks ----------------
// Block b owns features [b*16, b*16+16). Thread t: fi = t&15 (feature),
// ci = t>>4 (chunk lane, 16 lanes per feature). Consecutive lanes read
// consecutive float4s -> coalesced 256B segments.
__global__ void __launch_bounds__(TPB) cov_pass2(
    const float4* __restrict__ part, double* __restrict__ blk, int nchunk, int N) {
  const int fi = threadIdx.x & 15;
  const int ci = threadIdx.x >> 4;
  const int f = blockIdx.x * 16 + fi;

  double S[4] = {0.0, 0.0, 0.0, 0.0};
  for (int c = ci; c < nchunk; c += 16) {
    float4 p = part[(size_t)c * F_DIM + f];
    S[0] += (double)p.x;
    S[1] += (double)p.y;
    S[2] += (double)p.z;
    S[3] += (double)p.w;
  }

  __shared__ double red[16][16][4];
#pragma unroll
  for (int m = 0; m < 4; ++m) red[ci][fi][m] = S[m];
  __syncthreads();

  __shared__ double loss_lds[16];
  if (threadIdx.x < 16) {                    // one thread per feature
    const int ff = threadIdx.x;
    double S1 = 0.0, S2 = 0.0, S3 = 0.0, S4 = 0.0;
    for (int c = 0; c < 16; ++c) {
      S1 += red[c][ff][0];
      S2 += red[c][ff][1];
      S3 += red[c][ff][2];
      S4 += red[c][ff][3];
    }
    const double n = (double)N;
    const double m = S1 / n;
    const double m2 = m * m;
    const double s2c = S2 - n * m2;
    const double s4c = S4 - 4.0 * m * S3 + 6.0 * m2 * S2 - 3.0 * n * m2 * m2;
    loss_lds[ff] = s2c * s2c - s4c;
  }
  __syncthreads();
  if (threadIdx.x == 0) {
    double s = 0.0;
    for (int i = 0; i < 16; ++i) s += loss_lds[i];
    blk[blockIdx.x] = s;
  }
}

// ---------------- Pass 3: final 256-wide reduce + scale ----------------
__global__ void __launch_bounds__(TPB) cov_pass3(
    const double* __restrict__ blk, int nblk, double scale, float* __restrict__ out) {
  __shared__ double red[TPB];
  double v = (threadIdx.x < nblk) ? blk[threadIdx.x] : 0.0;
  for (int i = threadIdx.x + TPB; i < nblk; i += TPB) v += blk[i];
  red[threadIdx.x] = v;
  __syncthreads();
  for (int s = TPB / 2; s > 0; s >>= 1) {
    if (threadIdx.x < s) red[threadIdx.x] += red[threadIdx.x + s];
    __syncthreads();
  }
  if (threadIdx.x == 0) out[0] = (float)(red[0] * scale);
}

extern "C" void kernel_launch(void* const* d_in, const int* in_sizes, int n_in,
                              void* d_out, int out_size, void* d_ws, size_t ws_size,
                              hipStream_t stream) {
  const float* zs = (const float*)d_in[0];
  float* out = (float*)d_out;
  const size_t total = (size_t)in_sizes[0];
  const int N = (int)(total / F_DIM);        // 16384 rows

  // nchunk=128: partials = 128*4096*16B = 8 MB (fits L2/LLC); grid 512 blocks.
  int nchunk = 128;
  while (nchunk > 1 &&
         ((size_t)nchunk * F_DIM * sizeof(float4) + 8192 > ws_size ||
          (N % nchunk) != 0)) {
    nchunk >>= 1;
  }
  const int rows_per_chunk = N / nchunk;

  float4* part = (float4*)d_ws;
  double* blk = (double*)((char*)d_ws + (size_t)nchunk * F_DIM * sizeof(float4));

  dim3 g1(F_DIM / FEAT_PER_BLOCK, nchunk);    // (4, 128) = 512 blocks
  cov_pass1<<<g1, TPB, 0, stream>>>(zs, part, rows_per_chunk);

  const int nblk2 = F_DIM / 16;               // 256 blocks
  cov_pass2<<<nblk2, TPB, 0, stream>>>(part, blk, nchunk, N);

  const double nm1 = (double)(N - 1);
  const double scale = 1.0 / (nm1 * nm1 * nm1 * (double)F_DIM);
  cov_pass3<<<1, TPB, 0, stream>>>(blk, nblk2, scale, out);
}